// Round 3
// baseline (1107.781 us; speedup 1.0000x reference)
//
#include <hip/hip_runtime.h>

// SSIM on (32,3,512,512) f32 — wave-autonomous separable 11-tap streaming.
// Each wave owns a 128-col x 64-row band: 64 lanes x 2 cols (float2).
// NO __syncthreads in the hot loop: LDS row buffer is wave-private and
// same-wave DS ops execute in order (read row i, then overwrite with row i+1).
// Vertical conv via 11 rotating float2 accumulators x 5 quantities (static
// indices from 11-step unroll; every-step reset per R2-verified schedule).
// Single kernel: per-block partials + device-fence counter; last block reduces.

#define NBLK 768
#define NSTEP 74            // 10 warmup + 64 emitted rows

__device__ __forceinline__ float2 f2z() { return make_float2(0.f, 0.f); }

__global__ __launch_bounds__(256, 3) void ssim_fused(
    const float* __restrict__ x, const float* __restrict__ y,
    const float* __restrict__ window,
    unsigned* __restrict__ counter, float* __restrict__ partials,
    float* __restrict__ out)
{
    const int tid  = threadIdx.x;
    const int lane = tid & 63;
    const int wv   = tid >> 6;
    const int W    = blockIdx.x * 4 + wv;   // 0..3071
    const int img  = W >> 5;                // 96 planes
    const int cb   = (W >> 3) & 3;          // 4 col bands x 128
    const int rb   = W & 7;                 // 8 row bands x 64
    const int r0   = rb << 6;
    const int c0   = cb << 7;

    const float* xplane = x + (size_t)img * 262144;
    const float* yplane = y + (size_t)img * 262144;

    // 1-D gaussian: row i of outer(g,g) sums to g_i (sum(g)=1). Uniform -> SGPR.
    float g[11];
    #pragma unroll
    for (int ii = 0; ii < 11; ++ii) {
        float s = 0.f;
        #pragma unroll
        for (int jj = 0; jj < 11; ++jj) s += window[ii * 11 + jj];
        g[ii] = s;
    }

    // Wave-private LDS row: 70 float2 slots. Slot k holds cols c0-6+2k, +1.
    // Main: lane t -> slot t+3. Halo: slots 0..2 (left), 67..69 (right).
    __shared__ float2 lsx[4][70];
    __shared__ float2 lsy[4][70];
    float2* sxw = lsx[wv];
    float2* syw = lsy[wv];

    const bool isHalo = lane < 6;
    const int  hslot  = (lane < 3) ? lane : (64 + lane);            // 0,1,2,67,68,69
    const int  hcol   = (lane < 3) ? (c0 - 6 + 2 * lane)
                                   : (c0 + 128 + 2 * (lane - 3));
    const bool hOK    = isHalo && (hcol >= 0) && (hcol < 511);      // hcol even
    const int  mcol   = c0 + 2 * lane;

    float2 acx[11], acy[11], acxx[11], acyy[11], acxy[11];
    #pragma unroll
    for (int s = 0; s < 11; ++s) {
        acx[s] = f2z(); acy[s] = f2z(); acxx[s] = f2z(); acyy[s] = f2z(); acxy[s] = f2z();
    }

    // Preload row r0-5 (zeros outside image).
    {
        const int rn = r0 - 5;
        float2 mx = f2z(), my = f2z(), hx = f2z(), hy = f2z();
        if (rn >= 0) {
            const float* xp = xplane + rn * 512;
            const float* yp = yplane + rn * 512;
            mx = *(const float2*)(xp + mcol);
            my = *(const float2*)(yp + mcol);
            if (hOK) { hx = *(const float2*)(xp + hcol); hy = *(const float2*)(yp + hcol); }
        }
        sxw[lane + 3] = mx; syw[lane + 3] = my;
        if (isHalo) { sxw[hslot] = hx; syw[hslot] = hy; }
    }

    float2 ts = f2z();
    const float C1 = 1e-4f, C2 = 9e-4f;

    for (int chunk = 0; chunk < 7; ++chunk) {
        #pragma unroll
        for (int rr = 0; rr < 11; ++rr) {
            const int i = chunk * 11 + rr;
            if (i < NSTEP) {
                // ---- prefetch row r0-4+i (used next step) ----
                const int rn = r0 - 4 + i;
                float2 mx = f2z(), my = f2z(), hx = f2z(), hy = f2z();
                if (i <= NSTEP - 2 && (unsigned)rn < 512u) {
                    const float* xp = xplane + rn * 512;
                    const float* yp = yplane + rn * 512;
                    mx = *(const float2*)(xp + mcol);
                    my = *(const float2*)(yp + mcol);
                    if (hOK) { hx = *(const float2*)(xp + hcol); hy = *(const float2*)(yp + hcol); }
                }

                // ---- horizontal conv of row r0-5+i, cols A=mcol, B=mcol+1 ----
                // val[u] = col c0+2*lane-6+u; A taps use u=j+1, B taps u=j+2.
                float sxA=0,syA=0,sxxA=0,syyA=0,sxyA=0;
                float sxB=0,syB=0,sxxB=0,syyB=0,sxyB=0;
                float c6x, c7x, c6y, c7y;   // vals 6,7 carried between phases
                {   // phase 1: slots lane..lane+3 -> vals 0..7, taps j=0..4
                    float vxa[8], vya[8];
                    #pragma unroll
                    for (int k = 0; k < 4; ++k) {
                        const float2 a = sxw[lane + k];
                        const float2 b = syw[lane + k];
                        vxa[2*k] = a.x; vxa[2*k+1] = a.y;
                        vya[2*k] = b.x; vya[2*k+1] = b.y;
                    }
                    #pragma unroll
                    for (int j = 0; j < 5; ++j) {
                        const float gj = g[j];
                        { const float xv = vxa[j+1], yv = vya[j+1];
                          const float t1 = gj * xv, t2 = gj * yv;
                          sxA += t1; syA += t2;
                          sxxA = fmaf(t1, xv, sxxA); syyA = fmaf(t2, yv, syyA); sxyA = fmaf(t1, yv, sxyA); }
                        { const float xv = vxa[j+2], yv = vya[j+2];
                          const float t1 = gj * xv, t2 = gj * yv;
                          sxB += t1; syB += t2;
                          sxxB = fmaf(t1, xv, sxxB); syyB = fmaf(t2, yv, syyB); sxyB = fmaf(t1, yv, sxyB); }
                    }
                    c6x = vxa[6]; c7x = vxa[7]; c6y = vya[6]; c7y = vya[7];
                }
                {   // phase 2: slots lane+4..lane+6 -> vals 8..13, taps j=5..10
                    float vxa[14], vya[14];
                    vxa[6] = c6x; vxa[7] = c7x; vya[6] = c6y; vya[7] = c7y;
                    #pragma unroll
                    for (int k = 4; k < 7; ++k) {
                        const float2 a = sxw[lane + k];
                        const float2 b = syw[lane + k];
                        vxa[2*k] = a.x; vxa[2*k+1] = a.y;
                        vya[2*k] = b.x; vya[2*k+1] = b.y;
                    }
                    #pragma unroll
                    for (int j = 5; j < 11; ++j) {
                        const float gj = g[j];
                        { const float xv = vxa[j+1], yv = vya[j+1];
                          const float t1 = gj * xv, t2 = gj * yv;
                          sxA += t1; syA += t2;
                          sxxA = fmaf(t1, xv, sxxA); syyA = fmaf(t2, yv, syyA); sxyA = fmaf(t1, yv, sxyA); }
                        { const float xv = vxa[j+2], yv = vya[j+2];
                          const float t1 = gj * xv, t2 = gj * yv;
                          sxB += t1; syB += t2;
                          sxxB = fmaf(t1, xv, sxxB); syyB = fmaf(t2, yv, syyB); sxyB = fmaf(t1, yv, sxyB); }
                    }
                }

                // ---- vertical accumulate into rotating slots (static idx) ----
                #pragma unroll
                for (int j = 0; j < 11; ++j) {
                    const int s = (rr + j) % 11;
                    const float wj = g[10 - j];
                    acx [s].x = fmaf(wj, sxA , acx [s].x); acx [s].y = fmaf(wj, sxB , acx [s].y);
                    acy [s].x = fmaf(wj, syA , acy [s].x); acy [s].y = fmaf(wj, syB , acy [s].y);
                    acxx[s].x = fmaf(wj, sxxA, acxx[s].x); acxx[s].y = fmaf(wj, sxxB, acxx[s].y);
                    acyy[s].x = fmaf(wj, syyA, acyy[s].x); acyy[s].y = fmaf(wj, syyB, acyy[s].y);
                    acxy[s].x = fmaf(wj, sxyA, acxy[s].x); acxy[s].y = fmaf(wj, sxyB, acxy[s].y);
                }

                // ---- emit (rows r0 .. r0+63) + reset slot rr every step ----
                {
                    const int s = rr;
                    if (i >= 10) {
                        { const float mux = acx[s].x, muy = acy[s].x;
                          const float mux2 = mux*mux, muy2 = muy*muy, muxy = mux*muy;
                          const float vvx = acxx[s].x - mux2, vvy = acyy[s].x - muy2, vxy = acxy[s].x - muxy;
                          const float num = fmaf(2.f, muxy, C1) * fmaf(2.f, vxy, C2);
                          const float den = (mux2 + muy2 + C1) * (vvx + vvy + C2);
                          ts.x += num * __builtin_amdgcn_rcpf(den); }
                        { const float mux = acx[s].y, muy = acy[s].y;
                          const float mux2 = mux*mux, muy2 = muy*muy, muxy = mux*muy;
                          const float vvx = acxx[s].y - mux2, vvy = acyy[s].y - muy2, vxy = acxy[s].y - muxy;
                          const float num = fmaf(2.f, muxy, C1) * fmaf(2.f, vxy, C2);
                          const float den = (mux2 + muy2 + C1) * (vvx + vvy + C2);
                          ts.y += num * __builtin_amdgcn_rcpf(den); }
                    }
                    acx[s] = f2z(); acy[s] = f2z(); acxx[s] = f2z(); acyy[s] = f2z(); acxy[s] = f2z();
                }

                // ---- write prefetched row (after all reads; same-wave order) ----
                sxw[lane + 3] = mx; syw[lane + 3] = my;
                if (isHalo) { sxw[hslot] = hx; syw[hslot] = hy; }
            }
        }
    }

    // ---- block partial: wave shuffle + cross-wave LDS ----
    float t = ts.x + ts.y;
    #pragma unroll
    for (int off = 32; off > 0; off >>= 1) t += __shfl_down(t, off, 64);
    __shared__ float wsum[4];
    __shared__ int   sflag;
    if (lane == 0) wsum[wv] = t;
    __syncthreads();
    if (tid == 0) {
        partials[blockIdx.x] = (wsum[0] + wsum[1]) + (wsum[2] + wsum[3]);
        __threadfence();                      // release partial
        const unsigned old = atomicAdd(counter, 1u);   // device-scope
        sflag = (old == NBLK - 1) ? 1 : 0;
    }
    __syncthreads();
    if (sflag) {                              // last block reduces everything
        __threadfence();                      // acquire others' partials
        double s = 0.0;
        for (int idx = tid; idx < NBLK; idx += 256) s += (double)partials[idx];
        #pragma unroll
        for (int off = 32; off > 0; off >>= 1) s += __shfl_down(s, off, 64);
        __shared__ double dsum[4];
        if (lane == 0) dsum[wv] = s;
        __syncthreads();
        if (tid == 0)
            out[0] = (float)(((dsum[0] + dsum[1]) + (dsum[2] + dsum[3])) / 25165824.0);
    }
}

extern "C" void kernel_launch(void* const* d_in, const int* in_sizes, int n_in,
                              void* d_out, int out_size, void* d_ws, size_t ws_size,
                              hipStream_t stream)
{
    const float* x = (const float*)d_in[0];
    const float* y = (const float*)d_in[1];
    const float* w = (const float*)d_in[2];
    unsigned* counter = (unsigned*)d_ws;                     // zeroed below
    float* partials   = (float*)((char*)d_ws + 256);         // 768 floats

    hipMemsetAsync(d_ws, 0, 4, stream);                      // capture-safe
    ssim_fused<<<NBLK, 256, 0, stream>>>(x, y, w, counter, partials, (float*)d_out);
}

// Round 4
// 305.897 us; speedup vs baseline: 3.6214x; 3.6214x over previous
//
#include <hip/hip_runtime.h>

// SSIM on (32,3,512,512) f32 — wave-autonomous separable 11-tap streaming.
// Each wave owns a 128-col x 64-row band: 64 lanes x 2 cols (float2).
// No __syncthreads in the hot loop (wave-private LDS row, same-wave DS order).
// R4: ALL register-resident state is named scalars (macro-generated) — R3 put
// the float2 acc[11] arrays in scratch (VGPR=84, WRITE_SIZE=1.5GB of spills).
// Vertical conv: 11 rotating named accumulators x 5 quantities; slot s gets
// tap weight g[(10-s+rr)%11] at step rr; emit+reset slot rr each step (R2 fix).

#define NBLK  768
#define NSTEP 74            // 10 warmup + 64 emitted rows

__device__ __forceinline__ float2 f2z() { return make_float2(0.f, 0.f); }

#define DECL_ACC(S) float2 AX##S=f2z(), AY##S=f2z(), AXX##S=f2z(), AYY##S=f2z(), AXY##S=f2z();

#define HTAP(J, EA, EB) { const float gj = g[J]; \
  { const float xv = x##EA, yv = y##EA; const float t1 = gj*xv, t2 = gj*yv; \
    sxA += t1; syA += t2; sxxA = fmaf(t1,xv,sxxA); syyA = fmaf(t2,yv,syyA); sxyA = fmaf(t1,yv,sxyA); } \
  { const float xv = x##EB, yv = y##EB; const float t1 = gj*xv, t2 = gj*yv; \
    sxB += t1; syB += t2; sxxB = fmaf(t1,xv,sxxB); syyB = fmaf(t2,yv,syyB); sxyB = fmaf(t1,yv,sxyB); } }

#define VACC(S, RR) { const float wj = g[(10 - (S) + (RR)) % 11]; \
  AX##S.x  = fmaf(wj, sxA , AX##S.x ); AX##S.y  = fmaf(wj, sxB , AX##S.y ); \
  AY##S.x  = fmaf(wj, syA , AY##S.x ); AY##S.y  = fmaf(wj, syB , AY##S.y ); \
  AXX##S.x = fmaf(wj, sxxA, AXX##S.x); AXX##S.y = fmaf(wj, sxxB, AXX##S.y); \
  AYY##S.x = fmaf(wj, syyA, AYY##S.x); AYY##S.y = fmaf(wj, syyB, AYY##S.y); \
  AXY##S.x = fmaf(wj, sxyA, AXY##S.x); AXY##S.y = fmaf(wj, sxyB, AXY##S.y); }

#define EMIT(S) { \
  { const float mux = AX##S.x, muy = AY##S.x; \
    const float mux2 = mux*mux, muy2 = muy*muy, muxy = mux*muy; \
    const float vvx = AXX##S.x - mux2, vvy = AYY##S.x - muy2, vxy = AXY##S.x - muxy; \
    const float num = fmaf(2.f, muxy, C1) * fmaf(2.f, vxy, C2); \
    const float den = (mux2 + muy2 + C1) * (vvx + vvy + C2); \
    ts.x += num * __builtin_amdgcn_rcpf(den); } \
  { const float mux = AX##S.y, muy = AY##S.y; \
    const float mux2 = mux*mux, muy2 = muy*muy, muxy = mux*muy; \
    const float vvx = AXX##S.y - mux2, vvy = AYY##S.y - muy2, vxy = AXY##S.y - muxy; \
    const float num = fmaf(2.f, muxy, C1) * fmaf(2.f, vxy, C2); \
    const float den = (mux2 + muy2 + C1) * (vvx + vvy + C2); \
    ts.y += num * __builtin_amdgcn_rcpf(den); } }

#define RESET(S) { AX##S=f2z(); AY##S=f2z(); AXX##S=f2z(); AYY##S=f2z(); AXY##S=f2z(); }

#define STEP(RR) { \
  const int i = ibase + (RR); \
  if (i < NSTEP) { \
    const int rn = r0 - 4 + i; \
    float2 mx=f2z(), my=f2z(), hx=f2z(), hy=f2z(); \
    if (i <= NSTEP-2 && (unsigned)rn < 512u) { \
      const float* xp = xplane + rn * 512; \
      const float* yp = yplane + rn * 512; \
      mx = *(const float2*)(xp + mcol); my = *(const float2*)(yp + mcol); \
      if (hOK) { hx = *(const float2*)(xp + hcol); hy = *(const float2*)(yp + hcol); } \
    } \
    const float2 xa0 = sxw[lane  ], xa1 = sxw[lane+1], xa2 = sxw[lane+2], xa3 = sxw[lane+3]; \
    const float2 xa4 = sxw[lane+4], xa5 = sxw[lane+5], xa6 = sxw[lane+6]; \
    const float2 ya0 = syw[lane  ], ya1 = syw[lane+1], ya2 = syw[lane+2], ya3 = syw[lane+3]; \
    const float2 ya4 = syw[lane+4], ya5 = syw[lane+5], ya6 = syw[lane+6]; \
    float sxA=0.f, syA=0.f, sxxA=0.f, syyA=0.f, sxyA=0.f; \
    float sxB=0.f, syB=0.f, sxxB=0.f, syyB=0.f, sxyB=0.f; \
    HTAP(0,a0.y,a1.x) HTAP(1,a1.x,a1.y) HTAP(2,a1.y,a2.x) HTAP(3,a2.x,a2.y) \
    HTAP(4,a2.y,a3.x) HTAP(5,a3.x,a3.y) HTAP(6,a3.y,a4.x) HTAP(7,a4.x,a4.y) \
    HTAP(8,a4.y,a5.x) HTAP(9,a5.x,a5.y) HTAP(10,a5.y,a6.x) \
    VACC(0,RR) VACC(1,RR) VACC(2,RR) VACC(3,RR) VACC(4,RR) VACC(5,RR) \
    VACC(6,RR) VACC(7,RR) VACC(8,RR) VACC(9,RR) VACC(10,RR) \
    if (i >= 10) { EMIT(RR) } \
    RESET(RR) \
    sxw[lane+3] = mx; syw[lane+3] = my; \
    if (isHalo) { sxw[hslot] = hx; syw[hslot] = hy; } \
  } }

__global__ __launch_bounds__(256, 2) void ssim_fused(
    const float* __restrict__ x, const float* __restrict__ y,
    const float* __restrict__ window,
    unsigned* __restrict__ counter, float* __restrict__ partials,
    float* __restrict__ out)
{
    const int tid  = threadIdx.x;
    const int lane = tid & 63;
    const int wv   = tid >> 6;
    const int W    = blockIdx.x * 4 + wv;   // 0..3071
    const int img  = W >> 5;                // 96 planes
    const int cb   = (W >> 3) & 3;          // 4 col bands x 128
    const int rb   = W & 7;                 // 8 row bands x 64
    const int r0   = rb << 6;
    const int c0   = cb << 7;

    const float* xplane = x + (size_t)img * 262144;
    const float* yplane = y + (size_t)img * 262144;

    // 1-D gaussian: row i of outer(g,g) sums to g_i (sum(g)=1). Uniform.
    float g[11];
    #pragma unroll
    for (int ii = 0; ii < 11; ++ii) {
        float s = 0.f;
        #pragma unroll
        for (int jj = 0; jj < 11; ++jj) s += window[ii * 11 + jj];
        g[ii] = s;
    }

    // Wave-private LDS row: 70 float2 slots; slot k = cols c0-6+2k, +1.
    __shared__ float2 lsx[4][70];
    __shared__ float2 lsy[4][70];
    float2* sxw = lsx[wv];
    float2* syw = lsy[wv];

    const bool isHalo = lane < 6;
    const int  hslot  = (lane < 3) ? lane : (64 + lane);        // 0,1,2,67,68,69
    const int  hcol   = (lane < 3) ? (c0 - 6 + 2 * lane)
                                   : (c0 + 128 + 2 * (lane - 3));
    const bool hOK    = isHalo && (hcol >= 0) && (hcol < 511);
    const int  mcol   = c0 + 2 * lane;

    DECL_ACC(0) DECL_ACC(1) DECL_ACC(2) DECL_ACC(3) DECL_ACC(4) DECL_ACC(5)
    DECL_ACC(6) DECL_ACC(7) DECL_ACC(8) DECL_ACC(9) DECL_ACC(10)

    // Preload row r0-5 (zeros outside image).
    {
        const int rn = r0 - 5;
        float2 mx = f2z(), my = f2z(), hx = f2z(), hy = f2z();
        if (rn >= 0) {
            const float* xp = xplane + rn * 512;
            const float* yp = yplane + rn * 512;
            mx = *(const float2*)(xp + mcol);
            my = *(const float2*)(yp + mcol);
            if (hOK) { hx = *(const float2*)(xp + hcol); hy = *(const float2*)(yp + hcol); }
        }
        sxw[lane + 3] = mx; syw[lane + 3] = my;
        if (isHalo) { sxw[hslot] = hx; syw[hslot] = hy; }
    }

    float2 ts = f2z();
    const float C1 = 1e-4f, C2 = 9e-4f;

    #pragma unroll 1
    for (int chunk = 0; chunk < 7; ++chunk) {
        const int ibase = chunk * 11;
        STEP(0) STEP(1) STEP(2) STEP(3) STEP(4) STEP(5)
        STEP(6) STEP(7) STEP(8) STEP(9) STEP(10)
    }

    // ---- block partial: wave shuffle + cross-wave LDS ----
    float t = ts.x + ts.y;
    #pragma unroll
    for (int off = 32; off > 0; off >>= 1) t += __shfl_down(t, off, 64);
    __shared__ float wsum[4];
    __shared__ int   sflag;
    if (lane == 0) wsum[wv] = t;
    __syncthreads();
    if (tid == 0) {
        partials[blockIdx.x] = (wsum[0] + wsum[1]) + (wsum[2] + wsum[3]);
        __threadfence();
        const unsigned old = atomicAdd(counter, 1u);
        sflag = (old == NBLK - 1) ? 1 : 0;
    }
    __syncthreads();
    if (sflag) {                              // last block reduces everything
        __threadfence();
        double s = 0.0;
        for (int idx = tid; idx < NBLK; idx += 256) s += (double)partials[idx];
        #pragma unroll
        for (int off = 32; off > 0; off >>= 1) s += __shfl_down(s, off, 64);
        __shared__ double dsum[4];
        if (lane == 0) dsum[wv] = s;
        __syncthreads();
        if (tid == 0)
            out[0] = (float)(((dsum[0] + dsum[1]) + (dsum[2] + dsum[3])) / 25165824.0);
    }
}

extern "C" void kernel_launch(void* const* d_in, const int* in_sizes, int n_in,
                              void* d_out, int out_size, void* d_ws, size_t ws_size,
                              hipStream_t stream)
{
    const float* x = (const float*)d_in[0];
    const float* y = (const float*)d_in[1];
    const float* w = (const float*)d_in[2];
    unsigned* counter = (unsigned*)d_ws;                     // zeroed below
    float* partials   = (float*)((char*)d_ws + 256);         // 768 floats

    hipMemsetAsync(d_ws, 0, 4, stream);                      // capture-safe
    ssim_fused<<<NBLK, 256, 0, stream>>>(x, y, w, counter, partials, (float*)d_out);
}